// Round 5
// baseline (106.735 us; speedup 1.0000x reference)
//
#include <hip/hip_runtime.h>
#include <math.h>

// Problem constants: B=8, T=64, R=100, TH=768, IH=1024, P=N=512
#define B_  8
#define T_  64
#define R_  100
#define TH_ 768
#define IH_ 1024
#define P_  512
#define N_  512

#define CTANH 2.88539008177792681f   // 2*log2(e): tanh(x) = 1 - 2/(1+exp2(CTANH*x))

typedef short short8  __attribute__((ext_vector_type(8)));
typedef float floatx4 __attribute__((ext_vector_type(4)));

__device__ __forceinline__ ushort f2bf(float f) {
  union { float f; unsigned int u; } v; v.f = f;
  unsigned int r = v.u + 0x7FFFu + ((v.u >> 16) & 1u);   // RNE
  return (ushort)(r >> 16);
}

// ---------------------------------------------------------------------------
// MFMA bf16 GEMM + bias + exact GELU (output pre-scaled by CTANH).
// Grid (8 col-tiles, 21 row-tiles: 0..7 Q [M=512,K=768], 8..20 K [M=800,K=1024]).
// 64x64 tile, BK=32, 256 threads = 4 waves; each wave one 32x32 quadrant via
// 2x2 mfma_f32_16x16x32_bf16. f32 inputs converted to bf16 during LDS staging.
// (unchanged from round 4 — passed with absmax 7.8e-3)
// ---------------------------------------------------------------------------
#define PADK 40

__global__ __launch_bounds__(256) void mfma_linear_gelu(
    const float* __restrict__ encT, const float* __restrict__ Wq,
    const float* __restrict__ bq, float* __restrict__ qout,
    const float* __restrict__ encI, const float* __restrict__ Wk,
    const float* __restrict__ bk, float* __restrict__ kout) {
  const int rt = blockIdx.y;
  const bool isQ = rt < 8;
  const float* __restrict__ X = isQ ? encT : encI;
  const float* __restrict__ W = isQ ? Wq : Wk;
  const float* __restrict__ bias = isQ ? bq : bk;
  float* __restrict__ Y = isQ ? qout : kout;
  const int M    = isQ ? (B_ * T_) : (B_ * R_);
  const int KDIM = isQ ? TH_ : IH_;
  const int row0 = (isQ ? rt : (rt - 8)) * 64;
  const int col0 = blockIdx.x * 64;
  const int ntiles = KDIM / 32;            // 24 (Q) or 32 (K)

  __shared__ ushort As[64 * PADK];         // As[m*PADK + k]
  __shared__ ushort Bs[64 * PADK];         // Bs[n*PADK + k]  (transposed B)

  const int tid = threadIdx.x;

  const int arow = tid >> 2;               // 0..63
  const int akq  = (tid & 3) * 8;          // 0,8,16,24
  const int arowc = min(row0 + arow, M - 1);
  const float* __restrict__ Xp = X + (size_t)arowc * KDIM + akq;

  const int bkp = (tid >> 4) * 2;          // 0,2,..,30
  const int bn4 = (tid & 15) * 4;          // 0,4,..,60
  const float* __restrict__ Wp = W + (size_t)bkp * N_ + col0 + bn4;

  const int wave = tid >> 6;               // 0..3
  const int lane = tid & 63;
  const int wm = (wave >> 1) * 32;
  const int wn = (wave & 1) * 32;
  const int l15 = lane & 15;
  const int q8  = (lane >> 4) * 8;

  floatx4 acc00 = {0.f,0.f,0.f,0.f}, acc01 = {0.f,0.f,0.f,0.f};
  floatx4 acc10 = {0.f,0.f,0.f,0.f}, acc11 = {0.f,0.f,0.f,0.f};

  float4 a0 = *(const float4*)(Xp + 0);
  float4 a1 = *(const float4*)(Xp + 4);
  float4 b0 = *(const float4*)(Wp);
  float4 b1 = *(const float4*)(Wp + N_);

  for (int kt = 0; kt < ntiles; ++kt) {
    {
      short8 pk;
      pk[0] = (short)f2bf(a0.x); pk[1] = (short)f2bf(a0.y);
      pk[2] = (short)f2bf(a0.z); pk[3] = (short)f2bf(a0.w);
      pk[4] = (short)f2bf(a1.x); pk[5] = (short)f2bf(a1.y);
      pk[6] = (short)f2bf(a1.z); pk[7] = (short)f2bf(a1.w);
      *(short8*)&As[arow * PADK + akq] = pk;
    }
    {
      unsigned int p0 = (unsigned int)f2bf(b0.x) | ((unsigned int)f2bf(b1.x) << 16);
      unsigned int p1 = (unsigned int)f2bf(b0.y) | ((unsigned int)f2bf(b1.y) << 16);
      unsigned int p2 = (unsigned int)f2bf(b0.z) | ((unsigned int)f2bf(b1.z) << 16);
      unsigned int p3 = (unsigned int)f2bf(b0.w) | ((unsigned int)f2bf(b1.w) << 16);
      *(unsigned int*)&Bs[(bn4 + 0) * PADK + bkp] = p0;
      *(unsigned int*)&Bs[(bn4 + 1) * PADK + bkp] = p1;
      *(unsigned int*)&Bs[(bn4 + 2) * PADK + bkp] = p2;
      *(unsigned int*)&Bs[(bn4 + 3) * PADK + bkp] = p3;
    }
    __syncthreads();

    if (kt + 1 < ntiles) {
      const int kb = (kt + 1) * 32;
      a0 = *(const float4*)(Xp + kb);
      a1 = *(const float4*)(Xp + kb + 4);
      b0 = *(const float4*)(W + (size_t)(kb + bkp) * N_ + col0 + bn4);
      b1 = *(const float4*)(W + (size_t)(kb + bkp + 1) * N_ + col0 + bn4);
    }

    short8 af0 = *(const short8*)&As[(wm + l15) * PADK + q8];
    short8 af1 = *(const short8*)&As[(wm + 16 + l15) * PADK + q8];
    short8 bf0 = *(const short8*)&Bs[(wn + l15) * PADK + q8];
    short8 bf1 = *(const short8*)&Bs[(wn + 16 + l15) * PADK + q8];
    acc00 = __builtin_amdgcn_mfma_f32_16x16x32_bf16(af0, bf0, acc00, 0, 0, 0);
    acc01 = __builtin_amdgcn_mfma_f32_16x16x32_bf16(af0, bf1, acc01, 0, 0, 0);
    acc10 = __builtin_amdgcn_mfma_f32_16x16x32_bf16(af1, bf0, acc10, 0, 0, 0);
    acc11 = __builtin_amdgcn_mfma_f32_16x16x32_bf16(af1, bf1, acc11, 0, 0, 0);
    __syncthreads();
  }

  const float is2 = 0.70710678118654752f;
  const float bia0 = bias[col0 + wn + l15];
  const float bia1 = bias[col0 + wn + 16 + l15];
  const int rbase = row0 + wm + (lane >> 4) * 4;

  #pragma unroll
  for (int r = 0; r < 4; ++r) {
    int row = rbase + r;
    if (row < M) {
      float v0 = acc00[r] + bia0;
      Y[(size_t)row * N_ + col0 + wn + l15] =
          CTANH * 0.5f * v0 * (1.f + erff(v0 * is2));
      float v1 = acc01[r] + bia1;
      Y[(size_t)row * N_ + col0 + wn + 16 + l15] =
          CTANH * 0.5f * v1 * (1.f + erff(v1 * is2));
    }
    int row2 = rbase + 16 + r;
    if (row2 < M) {
      float v2 = acc10[r] + bia0;
      Y[(size_t)row2 * N_ + col0 + wn + l15] =
          CTANH * 0.5f * v2 * (1.f + erff(v2 * is2));
      float v3 = acc11[r] + bia1;
      Y[(size_t)row2 * N_ + col0 + wn + 16 + l15] =
          CTANH * 0.5f * v3 * (1.f + erff(v3 * is2));
    }
  }
}

// ---------------------------------------------------------------------------
// Fusion, latency-hiding rewrite: ONE WAVE = ONE rg (4 r's, 16 lanes each).
// Grid (512 bt, 7 rg-groups) x 256 thr = 12800 active waves (~12.5/SIMD).
// Per lane: 32 elems (8 float4 each of q,k,w), acc += w*(1-2/(1+exp2(q'+k'))),
// then a 4-step 16-lane reduce. No sumw prologue, no per-wave looping.
// ---------------------------------------------------------------------------
__global__ __launch_bounds__(256) void fuse_kernel(
    const float* __restrict__ q, const float* __restrict__ k,
    const float* __restrict__ w, const float* __restrict__ bscalar,
    const float* __restrict__ mask, float* __restrict__ out) {
  const int bt = blockIdx.x;               // 0..511
  const int wave = threadIdx.x >> 6;
  const int rg = blockIdx.y * 4 + wave;    // 0..27
  if (rg >= 25) return;                    // whole-wave exit, no barriers used
  const int lane = threadIdx.x & 63;
  const int sub  = lane >> 4;              // r within group of 4
  const int pi   = lane & 15;              // p-slice
  const int r = rg * 4 + sub;              // 0..99
  const int b = bt >> 6;

  const float* __restrict__ qp = q + (size_t)bt * P_ + pi * 4;
  const float* __restrict__ kp = k + (size_t)(b * R_ + r) * P_ + pi * 4;
  const float* __restrict__ wp = w + pi * 4;

  float acc0 = 0.f, acc1 = 0.f;
  #pragma unroll
  for (int i = 0; i < 8; ++i) {
    float4 qv = *(const float4*)(qp + i * 64);
    float4 kv = *(const float4*)(kp + i * 64);
    float4 wv = *(const float4*)(wp + i * 64);
    float x, e, d, s;
    x = qv.x + kv.x;
    e = __builtin_amdgcn_exp2f(x);
    d = __builtin_amdgcn_rcpf(1.f + e);
    s = fmaf(-2.f, d, 1.f);
    acc0 = fmaf(wv.x, s, acc0);
    x = qv.y + kv.y;
    e = __builtin_amdgcn_exp2f(x);
    d = __builtin_amdgcn_rcpf(1.f + e);
    s = fmaf(-2.f, d, 1.f);
    acc1 = fmaf(wv.y, s, acc1);
    x = qv.z + kv.z;
    e = __builtin_amdgcn_exp2f(x);
    d = __builtin_amdgcn_rcpf(1.f + e);
    s = fmaf(-2.f, d, 1.f);
    acc0 = fmaf(wv.z, s, acc0);
    x = qv.w + kv.w;
    e = __builtin_amdgcn_exp2f(x);
    d = __builtin_amdgcn_rcpf(1.f + e);
    s = fmaf(-2.f, d, 1.f);
    acc1 = fmaf(wv.w, s, acc1);
  }
  float acc = acc0 + acc1;
  #pragma unroll
  for (int off = 1; off < 16; off <<= 1) acc += __shfl_xor(acc, off, 64);

  if (pi == 0) {
    out[(size_t)bt * R_ + r] = acc + bscalar[0] + mask[(size_t)bt * R_ + r];
  }
}

// ---------------------------------------------------------------------------
extern "C" void kernel_launch(void* const* d_in, const int* in_sizes, int n_in,
                              void* d_out, int out_size, void* d_ws, size_t ws_size,
                              hipStream_t stream) {
  const float* encT = (const float*)d_in[0];
  const float* encI = (const float*)d_in[1];
  const float* mask = (const float*)d_in[2];
  const float* Wq   = (const float*)d_in[3];
  const float* bq   = (const float*)d_in[4];
  const float* Wk   = (const float*)d_in[5];
  const float* bk   = (const float*)d_in[6];
  const float* w    = (const float*)d_in[7];
  const float* bsc  = (const float*)d_in[8];
  float* out = (float*)d_out;

  float* q = (float*)d_ws;                 // [512, 512] f32, CTANH-prescaled
  float* k = q + (size_t)B_ * T_ * P_;     // [800, 512] f32, CTANH-prescaled

  dim3 grid(N_ / 64, 8 + 13);
  mfma_linear_gelu<<<grid, 256, 0, stream>>>(encT, Wq, bq, q, encI, Wk, bk, k);

  fuse_kernel<<<dim3(512, 7), 256, 0, stream>>>(q, k, w, bsc, mask, out);
}

// Round 6
// 95.857 us; speedup vs baseline: 1.1135x; 1.1135x over previous
//
#include <hip/hip_runtime.h>
#include <hip/hip_fp16.h>
#include <math.h>

// Problem constants: B=8, T=64, R=100, TH=768, IH=1024, P=N=512
#define B_  8
#define T_  64
#define R_  100
#define TH_ 768
#define IH_ 1024
#define P_  512
#define N_  512

#define CTANH 2.88539008177792681f   // 2*log2(e): tanh(x) = 1 - 2/(1+exp2(CTANH*x))

typedef short short8  __attribute__((ext_vector_type(8)));
typedef float floatx4 __attribute__((ext_vector_type(4)));

__device__ __forceinline__ ushort f2bf(float f) {
  union { float f; unsigned int u; } v; v.f = f;
  unsigned int r = v.u + 0x7FFFu + ((v.u >> 16) & 1u);   // RNE
  return (ushort)(r >> 16);
}

// ---------------------------------------------------------------------------
// MFMA bf16 GEMM + bias + exact GELU -> f16 out (pre-scaled by CTANH).
// In-block split-K=4: 1024 threads = 4 splits x 4 waves. Tile 64m x 32n.
// Grid (16 col-tiles, 21 row-tiles: 0..7 Q [M=512,K=768], 8..20 K [M=800,K=1024])
// = 336 blocks. Each split runs an independent [stage->mfma] pipeline over its
// k-quarter (6 or 8 BK=32 iters, vs 24/32 before), then LDS tree-reduce.
// Rationale: R4 gemm was 27.3us at 0.65 waves/SIMD -- latency-chain-bound.
// ---------------------------------------------------------------------------
#define PADK 40

__global__ __launch_bounds__(1024) void mfma_linear_gelu_sk4(
    const float* __restrict__ encT, const float* __restrict__ Wq,
    const float* __restrict__ bq, __half* __restrict__ qout,
    const float* __restrict__ encI, const float* __restrict__ Wk,
    const float* __restrict__ bk, __half* __restrict__ kout) {
  const int rt = blockIdx.y;
  const bool isQ = rt < 8;
  const float* __restrict__ X = isQ ? encT : encI;
  const float* __restrict__ W = isQ ? Wq : Wk;
  const float* __restrict__ bias = isQ ? bq : bk;
  __half* __restrict__ Y = isQ ? qout : kout;
  const int M    = isQ ? (B_ * T_) : (B_ * R_);
  const int KDIM = isQ ? TH_ : IH_;
  const int row0 = (isQ ? rt : (rt - 8)) * 64;
  const int col0 = blockIdx.x * 32;
  const int kq   = KDIM >> 2;              // k-quarter: 192 or 256
  const int ntiles = kq / 32;              // 6 (Q) or 8 (K)

  __shared__ ushort As[4][64 * PADK];      // per-split A: As[sp][m*PADK+k]
  __shared__ ushort Bs[4][32 * PADK];      // per-split B^T: Bs[sp][n*PADK+k]
  __shared__ float  red[2][64 * 33];       // reduce buffers (row-padded)

  const int tid = threadIdx.x;
  const int sp  = tid >> 8;                // split 0..3
  const int t   = tid & 255;
  const int kbase = sp * kq;

  // A loader (per split): row t>>2, k-chunk (t&3)*8
  const int arow = t >> 2;
  const int akq  = (t & 3) * 8;
  const int arowc = min(row0 + arow, M - 1);
  const float* __restrict__ Xp = X + (size_t)arowc * KDIM + kbase + akq;

  // B loader (per split): k-pair (t>>4)*2, col-pair (t&15)*2
  const int bkp = (t >> 4) * 2;
  const int bn2 = (t & 15) * 2;
  const float* __restrict__ Wp = W + (size_t)(kbase + bkp) * N_ + col0 + bn2;

  // compute mapping: wave within split covers 16 rows x 32 cols
  const int wv = t >> 6;                   // 0..3
  const int lane = t & 63;
  const int wm = wv * 16;
  const int l15 = lane & 15;
  const int q8  = (lane >> 4) * 8;
  const int q4  = (lane >> 4) * 4;

  floatx4 acc0 = {0.f,0.f,0.f,0.f}, acc1 = {0.f,0.f,0.f,0.f};

  float4 a0 = *(const float4*)(Xp);
  float4 a1 = *(const float4*)(Xp + 4);
  float2 b0 = *(const float2*)(Wp);
  float2 b1 = *(const float2*)(Wp + N_);

  for (int kt = 0; kt < ntiles; ++kt) {
    {
      short8 pk;
      pk[0] = (short)f2bf(a0.x); pk[1] = (short)f2bf(a0.y);
      pk[2] = (short)f2bf(a0.z); pk[3] = (short)f2bf(a0.w);
      pk[4] = (short)f2bf(a1.x); pk[5] = (short)f2bf(a1.y);
      pk[6] = (short)f2bf(a1.z); pk[7] = (short)f2bf(a1.w);
      *(short8*)&As[sp][arow * PADK + akq] = pk;
    }
    {
      unsigned int p0 = (unsigned int)f2bf(b0.x) | ((unsigned int)f2bf(b1.x) << 16);
      unsigned int p1 = (unsigned int)f2bf(b0.y) | ((unsigned int)f2bf(b1.y) << 16);
      *(unsigned int*)&Bs[sp][(bn2 + 0) * PADK + bkp] = p0;
      *(unsigned int*)&Bs[sp][(bn2 + 1) * PADK + bkp] = p1;
    }
    __syncthreads();

    if (kt + 1 < ntiles) {
      const int kb = (kt + 1) * 32;
      a0 = *(const float4*)(Xp + kb);
      a1 = *(const float4*)(Xp + kb + 4);
      b0 = *(const float2*)(Wp + (size_t)kb * N_);
      b1 = *(const float2*)(Wp + (size_t)(kb + 1) * N_);
    }

    short8 af  = *(const short8*)&As[sp][(wm + l15) * PADK + q8];
    short8 bf0 = *(const short8*)&Bs[sp][(l15) * PADK + q8];
    short8 bf1 = *(const short8*)&Bs[sp][(16 + l15) * PADK + q8];
    acc0 = __builtin_amdgcn_mfma_f32_16x16x32_bf16(af, bf0, acc0, 0, 0, 0);
    acc1 = __builtin_amdgcn_mfma_f32_16x16x32_bf16(af, bf1, acc1, 0, 0, 0);
    __syncthreads();
  }

  // cross-split reduce: splits 2,3 -> layers 0,1; add into 0,1; split1 -> layer0
  if (sp >= 2) {
    float* L = red[sp - 2];
    #pragma unroll
    for (int j = 0; j < 4; ++j) {
      L[(wm + q4 + j) * 33 + l15]      = acc0[j];
      L[(wm + q4 + j) * 33 + 16 + l15] = acc1[j];
    }
  }
  __syncthreads();
  if (sp < 2) {
    const float* L = red[sp];
    #pragma unroll
    for (int j = 0; j < 4; ++j) {
      acc0[j] += L[(wm + q4 + j) * 33 + l15];
      acc1[j] += L[(wm + q4 + j) * 33 + 16 + l15];
    }
  }
  __syncthreads();
  if (sp == 1) {
    float* L = red[0];
    #pragma unroll
    for (int j = 0; j < 4; ++j) {
      L[(wm + q4 + j) * 33 + l15]      = acc0[j];
      L[(wm + q4 + j) * 33 + 16 + l15] = acc1[j];
    }
  }
  __syncthreads();
  if (sp == 0) {
    const float* L = red[0];
    const float is2 = 0.70710678118654752f;
    const float bia0 = bias[col0 + l15];
    const float bia1 = bias[col0 + 16 + l15];
    #pragma unroll
    for (int j = 0; j < 4; ++j) {
      const int row = row0 + wm + q4 + j;
      if (row < M) {
        float v0 = acc0[j] + L[(wm + q4 + j) * 33 + l15] + bia0;
        float v1 = acc1[j] + L[(wm + q4 + j) * 33 + 16 + l15] + bia1;
        v0 = CTANH * 0.5f * v0 * (1.f + erff(v0 * is2));
        v1 = CTANH * 0.5f * v1 * (1.f + erff(v1 * is2));
        Y[(size_t)row * N_ + col0 + l15]      = __float2half(v0);
        Y[(size_t)row * N_ + col0 + 16 + l15] = __float2half(v1);
      }
    }
  }
}

// ---------------------------------------------------------------------------
// Fusion on f16 q/k: out[b,t,r] = sum_p w*(1 - 2/(1+exp2(q'+k'))) + b + mask.
// One wave = one rg (4 r's, 16 lanes each, 32 p/lane). Grid (512, 7).
// f16 halves the q/k bytes and load instrs (R2->R4 evidence: fuse scales with
// the load/instr stream, not TLP). pk_add in f16, transcendentals in f32.
// ---------------------------------------------------------------------------
__global__ __launch_bounds__(256) void fuse_kernel_h(
    const __half* __restrict__ q, const __half* __restrict__ k,
    const float* __restrict__ w, const float* __restrict__ bscalar,
    const float* __restrict__ mask, float* __restrict__ out) {
  const int bt = blockIdx.x;               // 0..511
  const int wave = threadIdx.x >> 6;
  const int rg = blockIdx.y * 4 + wave;    // 0..27
  if (rg >= 25) return;                    // whole-wave exit; no barriers used
  const int lane = threadIdx.x & 63;
  const int sub  = lane >> 4;              // r within group of 4
  const int pi   = lane & 15;              // p-slice
  const int r = rg * 4 + sub;              // 0..99
  const int b = bt >> 6;

  const __half* __restrict__ qp = q + (size_t)bt * P_ + pi * 8;
  const __half* __restrict__ kp = k + (size_t)(b * R_ + r) * P_ + pi * 8;
  const float* __restrict__ wp = w + pi * 8;

  float acc0 = 0.f, acc1 = 0.f;
  #pragma unroll
  for (int i = 0; i < 4; ++i) {
    union { float4 f; __half2 h[4]; } qu, ku;
    qu.f = *(const float4*)(qp + i * 128);
    ku.f = *(const float4*)(kp + i * 128);
    float4 w0 = *(const float4*)(wp + i * 128);
    float4 w1 = *(const float4*)(wp + i * 128 + 4);
    #pragma unroll
    for (int e = 0; e < 4; ++e) {
      __half2 s = __hadd2(qu.h[e], ku.h[e]);
      float x0 = __low2float(s);
      float x1 = __high2float(s);
      float d0 = __builtin_amdgcn_rcpf(1.f + __builtin_amdgcn_exp2f(x0));
      float d1 = __builtin_amdgcn_rcpf(1.f + __builtin_amdgcn_exp2f(x1));
      float s0 = fmaf(-2.f, d0, 1.f);
      float s1 = fmaf(-2.f, d1, 1.f);
      const float we0 = (e == 0) ? w0.x : (e == 1) ? w0.z : (e == 2) ? w1.x : w1.z;
      const float we1 = (e == 0) ? w0.y : (e == 1) ? w0.w : (e == 2) ? w1.y : w1.w;
      acc0 = fmaf(we0, s0, acc0);
      acc1 = fmaf(we1, s1, acc1);
    }
  }
  float acc = acc0 + acc1;
  #pragma unroll
  for (int off = 1; off < 16; off <<= 1) acc += __shfl_xor(acc, off, 64);

  if (pi == 0) {
    out[(size_t)bt * R_ + r] = acc + bscalar[0] + mask[(size_t)bt * R_ + r];
  }
}

// ---------------------------------------------------------------------------
extern "C" void kernel_launch(void* const* d_in, const int* in_sizes, int n_in,
                              void* d_out, int out_size, void* d_ws, size_t ws_size,
                              hipStream_t stream) {
  const float* encT = (const float*)d_in[0];
  const float* encI = (const float*)d_in[1];
  const float* mask = (const float*)d_in[2];
  const float* Wq   = (const float*)d_in[3];
  const float* bq   = (const float*)d_in[4];
  const float* Wk   = (const float*)d_in[5];
  const float* bk   = (const float*)d_in[6];
  const float* w    = (const float*)d_in[7];
  const float* bsc  = (const float*)d_in[8];
  float* out = (float*)d_out;

  __half* q = (__half*)d_ws;               // [512, 512] f16, CTANH-prescaled
  __half* k = q + (size_t)B_ * T_ * P_;    // [800, 512] f16, CTANH-prescaled

  dim3 grid(N_ / 32, 8 + 13);              // 336 blocks x 1024 threads
  mfma_linear_gelu_sk4<<<grid, 1024, 0, stream>>>(encT, Wq, bq, q,
                                                  encI, Wk, bk, k);

  fuse_kernel_h<<<dim3(512, 7), 256, 0, stream>>>(q, k, w, bsc, mask, out);
}